// Round 1
// baseline (2156.011 us; speedup 1.0000x reference)
//
#include <hip/hip_runtime.h>
#include <math.h>

#define QN 8
#define CN 1024
#define DN 256
#define NROWS 32768
#define RPW 64

#define LOSS_OFF 8388608
#define IDX_OFF  8388609

// Kernel 1: normalize codebooks and store transposed: cbnt[q][k][c] = cb[q][c][k] / max(||cb[q][c]||, 1e-12)
// One wave per codeword; also zeroes the loss accumulator cell.
__global__ void rvq_normalize_cb(const float* __restrict__ cb,
                                 float* __restrict__ cbnt,
                                 float* __restrict__ out) {
    if (blockIdx.x == 0 && threadIdx.x == 0) out[LOSS_OFF] = 0.0f;
    const int wave = threadIdx.x >> 6;
    const int lane = threadIdx.x & 63;
    const int cw = blockIdx.x * 4 + wave;          // 0..8191
    const int q = cw >> 10;
    const int c = cw & (CN - 1);
    float4 v = reinterpret_cast<const float4*>(cb + (size_t)cw * DN)[lane];
    float ss = v.x * v.x + v.y * v.y + v.z * v.z + v.w * v.w;
#pragma unroll
    for (int m = 1; m < 64; m <<= 1) ss += __shfl_xor(ss, m, 64);
    const float inv = 1.0f / fmaxf(sqrtf(ss), 1e-12f);
    float* dst = cbnt + (size_t)q * (DN * CN) + (size_t)(lane * 4) * CN + c;
    dst[0 * CN] = v.x * inv;
    dst[1 * CN] = v.y * inv;
    dst[2 * CN] = v.z * inv;
    dst[3 * CN] = v.w * inv;
}

// Kernel 2: persistent RVQ. Each WG owns 64 rows through all 8 stages.
// Residual transposed in LDS At[k][row]; sim GEMM fully on VALU f32.
__global__ __launch_bounds__(256, 2)
void rvq_main(const float* __restrict__ in,
              const float* __restrict__ cb,
              const float* __restrict__ cbnt,
              float* __restrict__ out) {
    __shared__ float At[DN][RPW];    // 64 KiB: residual, transposed [k][row]
    __shared__ float Bt[16][256];    // 16 KiB: normalized codebook k-slice [k][cod]
    int* sIdx = reinterpret_cast<int*>(&Bt[0][0]);   // alias; only used between GEMM phases

    const int t    = threadIdx.x;
    const int ty   = t >> 4;        // 0..15 -> rows ty*4..+3
    const int tx   = t & 15;        // 0..15 -> cod group
    const int rowq = t & 63;        // row for elementwise phases
    const int kgrp = t >> 6;        // 0..3
    const int base = blockIdx.x * RPW;

    // residual := inputs  (per-lane 16B reads; At writes are 2-way bank aliased = free)
#pragma unroll
    for (int i = 0; i < 16; ++i) {
        const int kb = kgrp * 4 + i * 16;
        float4 v = *reinterpret_cast<const float4*>(in + (size_t)(base + rowq) * DN + kb);
        At[kb + 0][rowq] = v.x;
        At[kb + 1][rowq] = v.y;
        At[kb + 2][rowq] = v.z;
        At[kb + 3][rowq] = v.w;
    }

    float lossAcc = 0.0f;

    for (int q = 0; q < QN; ++q) {
        const float* cbq  = cb   + (size_t)q * (CN * DN);
        const float* cbtq = cbnt + (size_t)q * (DN * CN);
        float runV[4];
        int   runI[4];
#pragma unroll
        for (int r = 0; r < 4; ++r) { runV[r] = -INFINITY; runI[r] = 0; }

        for (int chunk = 0; chunk < 4; ++chunk) {       // 4 chunks x 256 cods
            float4 acc[4][4];                            // [row][cc] of 4 cods each
#pragma unroll
            for (int r = 0; r < 4; ++r)
#pragma unroll
                for (int cc = 0; cc < 4; ++cc)
                    acc[r][cc] = make_float4(0.f, 0.f, 0.f, 0.f);

            // register prefetch of first B k-slice
            float4 st[4];
#pragma unroll
            for (int p = 0; p < 4; ++p)
                st[p] = *reinterpret_cast<const float4*>(
                    cbtq + (size_t)(p * 4 + kgrp) * CN + chunk * 256 + (t & 63) * 4);

            for (int kc = 0; kc < 16; ++kc) {           // K tiles of 16
                __syncthreads();                         // Bt free (prev FMA done / At update done)
#pragma unroll
                for (int p = 0; p < 4; ++p)              // wave-contiguous 1KiB writes: conflict-free
                    *reinterpret_cast<float4*>(&Bt[p * 4 + kgrp][(t & 63) * 4]) = st[p];
                if (kc < 15) {                           // issue next-tile loads; latency hides under FMA
                    const float* g = cbtq + (size_t)(kc + 1) * 16 * CN + chunk * 256 + (t & 63) * 4;
#pragma unroll
                    for (int p = 0; p < 4; ++p)
                        st[p] = *reinterpret_cast<const float4*>(g + (size_t)(p * 4 + kgrp) * CN);
                }
                __syncthreads();
#pragma unroll
                for (int k = 0; k < 16; ++k) {
                    const float4 a = *reinterpret_cast<const float4*>(&At[kc * 16 + k][ty * 4]);
                    const float ar[4] = { a.x, a.y, a.z, a.w };
#pragma unroll
                    for (int cc = 0; cc < 4; ++cc) {
                        const float4 b = *reinterpret_cast<const float4*>(&Bt[k][cc * 64 + tx * 4]);
#pragma unroll
                        for (int r = 0; r < 4; ++r) {
                            acc[r][cc].x = fmaf(ar[r], b.x, acc[r][cc].x);
                            acc[r][cc].y = fmaf(ar[r], b.y, acc[r][cc].y);
                            acc[r][cc].z = fmaf(ar[r], b.z, acc[r][cc].z);
                            acc[r][cc].w = fmaf(ar[r], b.w, acc[r][cc].w);
                        }
                    }
                }
            }

            // fold per-row best over this chunk (ascending cod, strict > keeps first max),
            // then butterfly all-reduce over the 16 tx lanes (tie -> lower index)
#pragma unroll
            for (int r = 0; r < 4; ++r) {
                float bv = -INFINITY;
                int bi = 0;
#pragma unroll
                for (int cc = 0; cc < 4; ++cc) {
                    const int cbase = chunk * 256 + cc * 64 + tx * 4;
                    const float vals[4] = { acc[r][cc].x, acc[r][cc].y, acc[r][cc].z, acc[r][cc].w };
#pragma unroll
                    for (int j = 0; j < 4; ++j)
                        if (vals[j] > bv) { bv = vals[j]; bi = cbase + j; }
                }
#pragma unroll
                for (int m = 1; m < 16; m <<= 1) {
                    const float ov = __shfl_xor(bv, m, 64);
                    const int   oi = __shfl_xor(bi, m, 64);
                    if (ov > bv || (ov == bv && oi < bi)) { bv = ov; bi = oi; }
                }
                if (bv > runV[r]) { runV[r] = bv; runI[r] = bi; }   // chunks ascend: > keeps earlier
            }
        }

        __syncthreads();                 // all Bt reads done before alias write
        if (tx == 0) {
#pragma unroll
            for (int r = 0; r < 4; ++r) sIdx[ty * 4 + r] = runI[r];
        }
        __syncthreads();
        if (t < 64) out[IDX_OFF + (size_t)q * NROWS + base + t] = (float)sIdx[t];

        // residual update + loss accumulation: r_new = r - cb[idx]; loss += r_new^2
        {
            const int gi = sIdx[rowq];
            const float* qrow = cbq + (size_t)gi * DN;
#pragma unroll
            for (int i = 0; i < 16; ++i) {
                const int kb = kgrp * 4 + i * 16;
                const float4 qv = *reinterpret_cast<const float4*>(qrow + kb);
                const float r0 = At[kb + 0][rowq] - qv.x;
                const float r1 = At[kb + 1][rowq] - qv.y;
                const float r2 = At[kb + 2][rowq] - qv.z;
                const float r3 = At[kb + 3][rowq] - qv.w;
                At[kb + 0][rowq] = r0;
                At[kb + 1][rowq] = r1;
                At[kb + 2][rowq] = r2;
                At[kb + 3][rowq] = r3;
                lossAcc += r0 * r0 + r1 * r1 + r2 * r2 + r3 * r3;
            }
        }
        __syncthreads();
    }

    // quantized_sum = inputs - residual_final
#pragma unroll
    for (int i = 0; i < 16; ++i) {
        const int kb = kgrp * 4 + i * 16;
        const float4 v = *reinterpret_cast<const float4*>(in + (size_t)(base + rowq) * DN + kb);
        float4 o;
        o.x = v.x - At[kb + 0][rowq];
        o.y = v.y - At[kb + 1][rowq];
        o.z = v.z - At[kb + 2][rowq];
        o.w = v.w - At[kb + 3][rowq];
        *reinterpret_cast<float4*>(out + (size_t)(base + rowq) * DN + kb) = o;
    }

    // loss: wave butterfly + cross-wave via LDS + one atomic per WG
#pragma unroll
    for (int m = 1; m < 64; m <<= 1) lossAcc += __shfl_xor(lossAcc, m, 64);
    __syncthreads();
    float* red = reinterpret_cast<float*>(&Bt[0][0]);
    if ((t & 63) == 0) red[t >> 6] = lossAcc;
    __syncthreads();
    if (t == 0) {
        const float tot = red[0] + red[1] + red[2] + red[3];
        atomicAdd(out + LOSS_OFF, tot * (1.25f / (8.0f * 8388608.0f)));
    }
}

extern "C" void kernel_launch(void* const* d_in, const int* in_sizes, int n_in,
                              void* d_out, int out_size, void* d_ws, size_t ws_size,
                              hipStream_t stream) {
    (void)in_sizes; (void)n_in; (void)out_size; (void)ws_size;
    const float* in   = (const float*)d_in[0];
    const float* cb   = (const float*)d_in[1];
    float* out        = (float*)d_out;
    float* cbnt       = (float*)d_ws;   // 8 MiB scratch: normalized+transposed codebooks

    rvq_normalize_cb<<<dim3(2048), dim3(256), 0, stream>>>(cb, cbnt, out);
    rvq_main<<<dim3(512), dim3(256), 0, stream>>>(in, cb, cbnt, out);
}

// Round 2
// 1827.681 us; speedup vs baseline: 1.1796x; 1.1796x over previous
//
#include <hip/hip_runtime.h>
#include <math.h>

#define QN 8
#define CN 1024
#define DN 256
#define NROWS 32768
#define RPW 64

#define LOSS_OFF 8388608
#define IDX_OFF  8388609

// ---------------------------------------------------------------------------
// Kernel 1: normalize codebooks, store transposed: cbnt[q][k][c] = cb[q][c][k]/max(||cb[q][c]||,1e-12)
// (unchanged from round 1 — verified correct)
// ---------------------------------------------------------------------------
__global__ void rvq_normalize_cb(const float* __restrict__ cb,
                                 float* __restrict__ cbnt,
                                 float* __restrict__ out) {
    if (blockIdx.x == 0 && threadIdx.x == 0) out[LOSS_OFF] = 0.0f;
    const int wave = threadIdx.x >> 6;
    const int lane = threadIdx.x & 63;
    const int cw = blockIdx.x * 4 + wave;          // 0..8191
    const int q = cw >> 10;
    const int c = cw & (CN - 1);
    float4 v = reinterpret_cast<const float4*>(cb + (size_t)cw * DN)[lane];
    float ss = v.x * v.x + v.y * v.y + v.z * v.z + v.w * v.w;
#pragma unroll
    for (int m = 1; m < 64; m <<= 1) ss += __shfl_xor(ss, m, 64);
    const float inv = 1.0f / fmaxf(sqrtf(ss), 1e-12f);
    float* dst = cbnt + (size_t)q * (DN * CN) + (size_t)(lane * 4) * CN + c;
    dst[0 * CN] = v.x * inv;
    dst[1 * CN] = v.y * inv;
    dst[2 * CN] = v.z * inv;
    dst[3 * CN] = v.w * inv;
}

// ---------------------------------------------------------------------------
// async global->LDS, 16B per lane. Dest is wave-uniform-base + lane*16 (HW
// semantics); we pass the per-lane address so both HW models agree.
// ---------------------------------------------------------------------------
__device__ __forceinline__ void async_copy16(float* lds_dst, const float* gsrc) {
    __builtin_amdgcn_global_load_lds(
        (const __attribute__((address_space(1))) unsigned int*)gsrc,
        (__attribute__((address_space(3))) unsigned int*)lds_dst,
        16, 0, 0);
}

// named accumulators: zero arrays -> zero scratch risk
#define DECL_ACC(r) \
    float4 c##r##_0 = make_float4(0.f,0.f,0.f,0.f), \
           c##r##_1 = make_float4(0.f,0.f,0.f,0.f), \
           c##r##_2 = make_float4(0.f,0.f,0.f,0.f), \
           c##r##_3 = make_float4(0.f,0.f,0.f,0.f);

#define FMA_RC(r, cc, b) \
    c##r##_##cc.x = fmaf(ar##r, b.x, c##r##_##cc.x); \
    c##r##_##cc.y = fmaf(ar##r, b.y, c##r##_##cc.y); \
    c##r##_##cc.z = fmaf(ar##r, b.z, c##r##_##cc.z); \
    c##r##_##cc.w = fmaf(ar##r, b.w, c##r##_##cc.w);

#define FOLD_CC(r, cc) { \
    const int cb_ = chunk * 256 + (cc) * 64 + tx * 4; \
    if (c##r##_##cc.x > bv) { bv = c##r##_##cc.x; bi = cb_ + 0; } \
    if (c##r##_##cc.y > bv) { bv = c##r##_##cc.y; bi = cb_ + 1; } \
    if (c##r##_##cc.z > bv) { bv = c##r##_##cc.z; bi = cb_ + 2; } \
    if (c##r##_##cc.w > bv) { bv = c##r##_##cc.w; bi = cb_ + 3; } }

#define FOLD_R(r, rv, ri) { \
    float bv = -INFINITY; int bi = 0; \
    FOLD_CC(r, 0) FOLD_CC(r, 1) FOLD_CC(r, 2) FOLD_CC(r, 3) \
    _Pragma("unroll") \
    for (int m = 1; m < 16; m <<= 1) { \
        const float ov = __shfl_xor(bv, m, 64); \
        const int   oi = __shfl_xor(bi, m, 64); \
        if (ov > bv || (ov == bv && oi < bi)) { bv = ov; bi = oi; } } \
    if (bv > rv) { rv = bv; ri = bi; } }

// ---------------------------------------------------------------------------
// Kernel 2: persistent RVQ. 64 rows/WG through all 8 stages.
// Residual transposed in LDS At[k][row]; B-tiles async-staged, double-buffered
// 8-k tiles, one barrier per tile (barrier's vmcnt drain = pipeline wait).
// Accumulation order per (row,cod) is k=0..255 sequential — identical numerics
// to the round-1 kernel that passed index validation.
// ---------------------------------------------------------------------------
__global__ __launch_bounds__(256, 2)
void rvq_main(const float* __restrict__ in,
              const float* __restrict__ cb,
              const float* __restrict__ cbnt,
              float* __restrict__ out) {
    __shared__ float At[DN][RPW];       // 64 KiB residual, transposed [k][row]
    __shared__ float Bt[2][8][256];     // 16 KiB: 2 x (8 k-rows x 256 cods)
    int* sIdx = reinterpret_cast<int*>(&Bt[0][0][0]);

    const int t    = threadIdx.x;
    const int ty   = t >> 4;            // 0..15 -> rows ty*4..+3
    const int tx   = t & 15;            // 0..15 -> cod group
    const int lane = t & 63;
    const int kgrp = t >> 6;            // wave id 0..3
    const int base = blockIdx.x * RPW;

    // residual := inputs (At writes: 2-way bank alias = free)
#pragma unroll
    for (int i = 0; i < 16; ++i) {
        const int kb = kgrp * 4 + i * 16;
        float4 v = *reinterpret_cast<const float4*>(in + (size_t)(base + lane) * DN + kb);
        At[kb + 0][lane] = v.x;
        At[kb + 1][lane] = v.y;
        At[kb + 2][lane] = v.z;
        At[kb + 3][lane] = v.w;
    }

    float lossAcc = 0.0f;

    for (int q = 0; q < QN; ++q) {
        const float* cbq  = cb   + (size_t)q * (CN * DN);
        const float* cbtq = cbnt + (size_t)q * (DN * CN);
        float rv0 = -INFINITY, rv1 = -INFINITY, rv2 = -INFINITY, rv3 = -INFINITY;
        int   ri0 = 0, ri1 = 0, ri2 = 0, ri3 = 0;

        for (int chunk = 0; chunk < 4; ++chunk) {       // 4 chunks x 256 cods
            DECL_ACC(0) DECL_ACC(1) DECL_ACC(2) DECL_ACC(3)

            // per-wave global source base: rows {kgrp*2, kgrp*2+1} of each tile
            const float* gsrc0 = cbtq + (size_t)chunk * 256 + (size_t)(kgrp * 2) * CN + lane * 4;

            // prologue: issue tile 0 into buf 0
            async_copy16(&Bt[0][kgrp * 2 + 0][lane * 4], gsrc0 + 0 * CN);
            async_copy16(&Bt[0][kgrp * 2 + 1][lane * 4], gsrc0 + 1 * CN);

            for (int tt = 0; tt < 32; ++tt) {           // 32 tiles x 8 k
                __syncthreads();                         // drains vmcnt: buf[tt&1] ready everywhere
                if (tt < 31) {                           // issue next tile; hides under FMA below
                    const float* g = gsrc0 + (size_t)((tt + 1) * 8) * CN;
                    const int nb = (tt + 1) & 1;
                    async_copy16(&Bt[nb][kgrp * 2 + 0][lane * 4], g + 0 * CN);
                    async_copy16(&Bt[nb][kgrp * 2 + 1][lane * 4], g + 1 * CN);
                }
                const int bb = tt & 1;
#pragma unroll
                for (int kk = 0; kk < 8; ++kk) {
                    const float4 a = *reinterpret_cast<const float4*>(&At[tt * 8 + kk][ty * 4]);
                    const float ar0 = a.x, ar1 = a.y, ar2 = a.z, ar3 = a.w;
                    const float4 b0 = *reinterpret_cast<const float4*>(&Bt[bb][kk][  0 + tx * 4]);
                    const float4 b1 = *reinterpret_cast<const float4*>(&Bt[bb][kk][ 64 + tx * 4]);
                    const float4 b2 = *reinterpret_cast<const float4*>(&Bt[bb][kk][128 + tx * 4]);
                    const float4 b3 = *reinterpret_cast<const float4*>(&Bt[bb][kk][192 + tx * 4]);
                    FMA_RC(0, 0, b0) FMA_RC(0, 1, b1) FMA_RC(0, 2, b2) FMA_RC(0, 3, b3)
                    FMA_RC(1, 0, b0) FMA_RC(1, 1, b1) FMA_RC(1, 2, b2) FMA_RC(1, 3, b3)
                    FMA_RC(2, 0, b0) FMA_RC(2, 1, b1) FMA_RC(2, 2, b2) FMA_RC(2, 3, b3)
                    FMA_RC(3, 0, b0) FMA_RC(3, 1, b1) FMA_RC(3, 2, b2) FMA_RC(3, 3, b3)
                }
            }
            // no outstanding async loads here (none issued for tt==31)

            // fold this chunk into running best (ascending cod, strict > == first max;
            // butterfly over the 16 tx lanes, tie -> lower index)
            FOLD_R(0, rv0, ri0)
            FOLD_R(1, rv1, ri1)
            FOLD_R(2, rv2, ri2)
            FOLD_R(3, rv3, ri3)
        }

        __syncthreads();                 // all Bt reads done before alias write
        if (tx == 0) {
            sIdx[ty * 4 + 0] = ri0;
            sIdx[ty * 4 + 1] = ri1;
            sIdx[ty * 4 + 2] = ri2;
            sIdx[ty * 4 + 3] = ri3;
        }
        __syncthreads();
        if (t < 64) out[IDX_OFF + (size_t)q * NROWS + base + t] = (float)sIdx[t];

        // residual update + loss: r_new = r - cb[idx]; loss += r_new^2
        {
            const int gi = sIdx[lane];
            const float* qrow = cbq + (size_t)gi * DN;
#pragma unroll
            for (int i = 0; i < 16; ++i) {
                const int kb = kgrp * 4 + i * 16;
                const float4 qv = *reinterpret_cast<const float4*>(qrow + kb);
                const float r0 = At[kb + 0][lane] - qv.x;
                const float r1 = At[kb + 1][lane] - qv.y;
                const float r2 = At[kb + 2][lane] - qv.z;
                const float r3 = At[kb + 3][lane] - qv.w;
                At[kb + 0][lane] = r0;
                At[kb + 1][lane] = r1;
                At[kb + 2][lane] = r2;
                At[kb + 3][lane] = r3;
                lossAcc += r0 * r0 + r1 * r1 + r2 * r2 + r3 * r3;
            }
        }
        __syncthreads();                 // At updated + sIdx free before next stage prologue
    }

    // quantized_sum = inputs - residual_final
#pragma unroll
    for (int i = 0; i < 16; ++i) {
        const int kb = kgrp * 4 + i * 16;
        const float4 v = *reinterpret_cast<const float4*>(in + (size_t)(base + lane) * DN + kb);
        float4 o;
        o.x = v.x - At[kb + 0][lane];
        o.y = v.y - At[kb + 1][lane];
        o.z = v.z - At[kb + 2][lane];
        o.w = v.w - At[kb + 3][lane];
        *reinterpret_cast<float4*>(out + (size_t)(base + lane) * DN + kb) = o;
    }

    // loss: wave butterfly + cross-wave via LDS + one atomic per WG
#pragma unroll
    for (int m = 1; m < 64; m <<= 1) lossAcc += __shfl_xor(lossAcc, m, 64);
    __syncthreads();
    float* red = reinterpret_cast<float*>(&Bt[0][0][0]);
    if (lane == 0) red[kgrp] = lossAcc;
    __syncthreads();
    if (t == 0) {
        const float tot = red[0] + red[1] + red[2] + red[3];
        atomicAdd(out + LOSS_OFF, tot * (1.25f / (8.0f * 8388608.0f)));
    }
}

extern "C" void kernel_launch(void* const* d_in, const int* in_sizes, int n_in,
                              void* d_out, int out_size, void* d_ws, size_t ws_size,
                              hipStream_t stream) {
    (void)in_sizes; (void)n_in; (void)out_size; (void)ws_size;
    const float* in   = (const float*)d_in[0];
    const float* cb   = (const float*)d_in[1];
    float* out        = (float*)d_out;
    float* cbnt       = (float*)d_ws;   // 8 MiB scratch: normalized+transposed codebooks

    rvq_normalize_cb<<<dim3(2048), dim3(256), 0, stream>>>(cb, cbnt, out);
    rvq_main<<<dim3(512), dim3(256), 0, stream>>>(in, cb, cbnt, out);
}